// Round 8
// baseline (272.341 us; speedup 1.0000x reference)
//
#include <hip/hip_runtime.h>
#include <math.h>

// Spherical harmonics edge attributes, lmax=2.
// Outputs (concat flat): edge_vec [E,3] | edge_length [E] | edge_sh [E,9]
//
// Round-8: grid-stride persistent blocks + 3-stage software pipeline.
// R7 counters showed: 108us, 1.88 TB/s (23% peak), VALUBusy 3.8%, occ 75%
// -> latency/queue bound, NOT BW/VALU bound. Two fixes:
//  (1) nt on ALL streaming accesses (idx, shift loads; every output store).
//      R7 used cache-allocating shift loads + out_sh stores -> 166MB streamed
//      through 4MiB/XCD L2 evicted the 1.2MB pos table -> gathers missed to
//      L3 and queued. nt keeps pos L2-resident (gathers ~200cy hits).
//  (2) 3-stage pipeline over the grid-stride loop, body order C,B,A:
//        C: compute+store edge k      (waits gathers(k), issued 1 iter ago)
//        B: issue gathers+shift(k+1)  (waits idx(k+1), issued 2 iters ago)
//        A: issue idx(k+2)
//      vmcnt is FIFO: each wait leaves the younger prefetches in flight, so
//      gather latency hides under a full iteration of compute+store issue.
// Pure function of input buffers: deterministic by construction.

#define SQRT3 1.7320508075688772f
#define SQRT5 2.2360679774997896f

__global__ __launch_bounds__(256) void sh_edge_kernel(
    const float*  __restrict__ pos,       // [N,3]
    const int*    __restrict__ edge_index,// [2,E]
    const float*  __restrict__ shift,     // [E,3]
    float* __restrict__ out_vec,          // [E,3]
    float* __restrict__ out_len,          // [E]
    float* __restrict__ out_sh,           // [E,9]
    int n_edges)
{
    const int stride = gridDim.x * 256;

    // ---------------- prologue ----------------
    int  e1 = blockIdx.x * 256 + threadIdx.x;
    bool a1 = e1 < n_edges;
    int  s1 = 0, d1 = 0;
    if (a1) {
        s1 = __builtin_nontemporal_load(&edge_index[e1]);
        d1 = __builtin_nontemporal_load(&edge_index[n_edges + e1]);
    }
    float ax1=0.f, ay1=0.f, az1=0.f, bx1=0.f, by1=0.f, bz1=0.f;
    float hx1=0.f, hy1=0.f, hz1=0.f;
    if (a1) {
        const float* ps = pos + 3 * (size_t)s1;   // regular loads: keep pos cached
        const float* pd = pos + 3 * (size_t)d1;
        ax1 = ps[0]; ay1 = ps[1]; az1 = ps[2];
        bx1 = pd[0]; by1 = pd[1]; bz1 = pd[2];
        const float* sp = shift + 3 * (size_t)e1;
        hx1 = __builtin_nontemporal_load(&sp[0]);
        hy1 = __builtin_nontemporal_load(&sp[1]);
        hz1 = __builtin_nontemporal_load(&sp[2]);
    }
    int  e2 = e1 + stride;
    bool a2 = e2 < n_edges;
    int  s2 = 0, d2 = 0;
    if (a2) {
        s2 = __builtin_nontemporal_load(&edge_index[e2]);
        d2 = __builtin_nontemporal_load(&edge_index[n_edges + e2]);
    }

    // ---------------- steady-state loop ----------------
    while (a1) {
        // ---- C: compute + store e1 (gathers(e1) issued >=1 iteration ago) ----
        {
            const float x = bx1 - ax1 - hx1;
            const float y = by1 - ay1 - hy1;
            const float z = bz1 - az1 - hz1;
            float* ov = out_vec + 3 * (size_t)e1;
            __builtin_nontemporal_store(x, &ov[0]);
            __builtin_nontemporal_store(y, &ov[1]);
            __builtin_nontemporal_store(z, &ov[2]);
            const float sq = x * x + y * y + z * z;
            const float r  = rsqrtf(sq);
            __builtin_nontemporal_store(sq * r, &out_len[e1]);
            const float nx = x * r, ny = y * r, nz = z * r;
            const float x2 = nx * nx, y2 = ny * ny, z2 = nz * nz;
            float* o = out_sh + 9 * (size_t)e1;
            __builtin_nontemporal_store(1.0f,                          &o[0]);
            __builtin_nontemporal_store(SQRT3 * nx,                    &o[1]);
            __builtin_nontemporal_store(SQRT3 * ny,                    &o[2]);
            __builtin_nontemporal_store(SQRT3 * nz,                    &o[3]);
            __builtin_nontemporal_store(SQRT5 * SQRT3 * nx * nz,       &o[4]);
            __builtin_nontemporal_store(SQRT5 * SQRT3 * nx * ny,       &o[5]);
            __builtin_nontemporal_store(SQRT5 * (y2 - 0.5f*(x2 + z2)), &o[6]);
            __builtin_nontemporal_store(SQRT5 * SQRT3 * ny * nz,       &o[7]);
            __builtin_nontemporal_store(SQRT5 * 0.5f * SQRT3 * (z2 - x2), &o[8]);
        }

        if (!a2) break;

        // ---- B: issue gathers + shift for e2 (idx(e2) issued 1-2 iters ago) ----
        float ax2, ay2, az2, bx2, by2, bz2, hx2, hy2, hz2;
        {
            const float* ps = pos + 3 * (size_t)s2;
            const float* pd = pos + 3 * (size_t)d2;
            ax2 = ps[0]; ay2 = ps[1]; az2 = ps[2];
            bx2 = pd[0]; by2 = pd[1]; bz2 = pd[2];
            const float* sp = shift + 3 * (size_t)e2;
            hx2 = __builtin_nontemporal_load(&sp[0]);
            hy2 = __builtin_nontemporal_load(&sp[1]);
            hz2 = __builtin_nontemporal_load(&sp[2]);
        }

        // ---- A: issue idx for e3 ----
        const int  e3 = e2 + stride;
        const bool a3 = e3 < n_edges;
        int s3 = 0, d3 = 0;
        if (a3) {
            s3 = __builtin_nontemporal_load(&edge_index[e3]);
            d3 = __builtin_nontemporal_load(&edge_index[n_edges + e3]);
        }

        // ---- rotate pipeline registers ----
        e1 = e2; a1 = a2;
        ax1 = ax2; ay1 = ay2; az1 = az2;
        bx1 = bx2; by1 = by2; bz1 = bz2;
        hx1 = hx2; hy1 = hy2; hz1 = hz2;
        e2 = e3; a2 = a3; s2 = s3; d2 = d3;
    }
}

extern "C" void kernel_launch(void* const* d_in, const int* in_sizes, int n_in,
                              void* d_out, int out_size, void* d_ws, size_t ws_size,
                              hipStream_t stream) {
    const float* pos        = (const float*)d_in[0];
    const int*   edge_index = (const int*)d_in[1];
    const float* shift      = (const float*)d_in[2];

    const int n_edges = in_sizes[2] / 3;   // shift is [E,3]

    float* out_vec = (float*)d_out;                        // [E,3]
    float* out_len = (float*)d_out + 3 * (size_t)n_edges;  // [E]
    float* out_sh  = (float*)d_out + 4 * (size_t)n_edges;  // [E,9]

    int blocks = (n_edges + 255) / 256;
    if (blocks > 2048) blocks = 2048;      // persistent grid-stride, ~8 blocks/CU
    sh_edge_kernel<<<blocks, 256, 0, stream>>>(
        pos, edge_index, shift, out_vec, out_len, out_sh, n_edges);
}

// Round 9
// 253.451 us; speedup vs baseline: 1.0745x; 1.0745x over previous
//
#include <hip/hip_runtime.h>
#include <math.h>

// Spherical harmonics edge attributes, lmax=2.
// Outputs (concat flat): edge_vec [E,3] | edge_length [E] | edge_sh [E,9]
//
// Round-9: persistent grid-stride + 3-stage pipeline + LDS-staged out_sh.
// Counter evidence so far:
//  R7: WRITE exactly 162.5MB with regular out_sh stores; 108us, VALU 3.8%
//  R8: nt scalar out_sh stores -> WRITE 258MB (+96MB partial-line
//      amplification); pipeline got 103us @ 2.9TB/s. FETCH only 36MB
//      (L3 keeps inputs resident). Floor ~200MB ~ 31us.
//  -> limiter = store-request throughput (13 scalar stride-36 stores/edge).
// Fixes:
//  - out_sh staged in LDS per 512-edge tile, flushed as full-line nt v4f
//    (4.5 store instrs/thread vs 18; no amplification, nt keeps L2 for pos)
//  - out_vec: merged dwordx3 nt stores (R7-verified exact write size)
//  - out_len: nt dword stores (stride-4, full coverage)
//  - 3-stage pipeline per block over tiles: idx(t+2) | gathers+shift(t+1)
//    | compute+flush(t). FIFO vmcnt: compute waits only its own (oldest)
//    loads; prefetches stay in flight across barriers.
// Pure function of input buffers: deterministic by construction.

#define SQRT3 1.7320508075688772f
#define SQRT5 2.2360679774997896f

typedef float v4f __attribute__((ext_vector_type(4)));

#define NTL(p)    __builtin_nontemporal_load(p)
#define NTS(v, p) __builtin_nontemporal_store((v), (p))

__global__ __launch_bounds__(256) void sh_edge_kernel(
    const float*  __restrict__ pos,       // [N,3]
    const int*    __restrict__ edge_index,// [2,E]
    const float*  __restrict__ shift,     // [E,3]
    float* __restrict__ out_vec,          // [E,3]
    float* __restrict__ out_len,          // [E]
    float* __restrict__ out_sh,           // [E,9]
    int n_edges)
{
    __shared__ float s_sh[4608];          // 512 edges x 9 = 18.4 KB
    const int tid     = threadIdx.x;
    const int n_tiles = (n_edges + 511) >> 9;
    const int tstride = gridDim.x;

    int t_cur = blockIdx.x;
    if (t_cur >= n_tiles) return;

    // ---- pipeline registers ----
    // current tile (compute-ready): gathers + shift for edge A (base+tid)
    // and edge B (base+tid+256)
    float aAx=0,aAy=0,aAz=0,bAx=0,bAy=0,bAz=0,hAx=0,hAy=0,hAz=0;
    float aBx=0,aBy=0,aBz=0,bBx=0,bBy=0,bBz=0,hBx=0,hBy=0,hBz=0;
    // next tile: indices only
    int nAs=0,nAd=0,nBs=0,nBd=0;

    // ---------------- prologue ----------------
    {
        const int base = t_cur << 9;
        const int eA = base + tid, eB = eA + 256;
        int sA=0,dA=0,sB=0,dB=0;
        const bool vA = eA < n_edges, vB = eB < n_edges;
        if (vA) { sA = NTL(&edge_index[eA]); dA = NTL(&edge_index[n_edges + eA]); }
        if (vB) { sB = NTL(&edge_index[eB]); dB = NTL(&edge_index[n_edges + eB]); }
        if (vA) {
            const float* p = pos + 3 * (size_t)sA; aAx=p[0]; aAy=p[1]; aAz=p[2];
            const float* q = pos + 3 * (size_t)dA; bAx=q[0]; bAy=q[1]; bAz=q[2];
            const float* sp = shift + 3 * (size_t)eA;
            hAx=NTL(&sp[0]); hAy=NTL(&sp[1]); hAz=NTL(&sp[2]);
        }
        if (vB) {
            const float* p = pos + 3 * (size_t)sB; aBx=p[0]; aBy=p[1]; aBz=p[2];
            const float* q = pos + 3 * (size_t)dB; bBx=q[0]; bBy=q[1]; bBz=q[2];
            const float* sp = shift + 3 * (size_t)eB;
            hBx=NTL(&sp[0]); hBy=NTL(&sp[1]); hBz=NTL(&sp[2]);
        }
    }
    int t_nxt = t_cur + tstride;
    if (t_nxt < n_tiles) {
        const int base = t_nxt << 9;
        const int eA = base + tid, eB = eA + 256;
        if (eA < n_edges) { nAs = NTL(&edge_index[eA]); nAd = NTL(&edge_index[n_edges + eA]); }
        if (eB < n_edges) { nBs = NTL(&edge_index[eB]); nBd = NTL(&edge_index[n_edges + eB]); }
    }

    // ---------------- steady-state loop ----------------
    while (true) {
        const int  base      = t_cur << 9;
        const bool have_next = (t_nxt < n_tiles);

        // ---- stage B: issue gathers + shift for t_nxt ----
        float xaAx=0,xaAy=0,xaAz=0,xbAx=0,xbAy=0,xbAz=0,xhAx=0,xhAy=0,xhAz=0;
        float xaBx=0,xaBy=0,xaBz=0,xbBx=0,xbBy=0,xbBz=0,xhBx=0,xhBy=0,xhBz=0;
        if (have_next) {
            const int nb = t_nxt << 9;
            const int eA = nb + tid, eB = eA + 256;
            if (eA < n_edges) {
                const float* p = pos + 3 * (size_t)nAs; xaAx=p[0]; xaAy=p[1]; xaAz=p[2];
                const float* q = pos + 3 * (size_t)nAd; xbAx=q[0]; xbAy=q[1]; xbAz=q[2];
                const float* sp = shift + 3 * (size_t)eA;
                xhAx=NTL(&sp[0]); xhAy=NTL(&sp[1]); xhAz=NTL(&sp[2]);
            }
            if (eB < n_edges) {
                const float* p = pos + 3 * (size_t)nBs; xaBx=p[0]; xaBy=p[1]; xaBz=p[2];
                const float* q = pos + 3 * (size_t)nBd; xbBx=q[0]; xbBy=q[1]; xbBz=q[2];
                const float* sp = shift + 3 * (size_t)eB;
                xhBx=NTL(&sp[0]); xhBy=NTL(&sp[1]); xhBz=NTL(&sp[2]);
            }
        }

        // ---- stage A: issue idx for t_nxt2 ----
        const int t_n2 = t_nxt + tstride;
        int mAs=0,mAd=0,mBs=0,mBd=0;
        if (t_n2 < n_tiles) {
            const int nb = t_n2 << 9;
            const int eA = nb + tid, eB = eA + 256;
            if (eA < n_edges) { mAs = NTL(&edge_index[eA]); mAd = NTL(&edge_index[n_edges + eA]); }
            if (eB < n_edges) { mBs = NTL(&edge_index[eB]); mBd = NTL(&edge_index[n_edges + eB]); }
        }

        // ---- stage C: compute t_cur (waits only its own, oldest, loads) ----
        const int nblk = min(512, n_edges - base);
#define EDGE_COMPUTE(k, AX,AY,AZ, BX,BY,BZ, HX,HY,HZ)                     \
        {                                                                 \
            const int e = base + (k);                                     \
            const float x = (BX) - (AX) - (HX);                           \
            const float y = (BY) - (AY) - (HY);                           \
            const float z = (BZ) - (AZ) - (HZ);                           \
            float* ov = out_vec + 3 * (size_t)e;                          \
            NTS(x, &ov[0]); NTS(y, &ov[1]); NTS(z, &ov[2]);               \
            const float sq = x*x + y*y + z*z;                             \
            const float r  = rsqrtf(sq);                                  \
            NTS(sq * r, &out_len[e]);                                     \
            const float nx = x*r, ny = y*r, nz = z*r;                     \
            const float x2 = nx*nx, y2 = ny*ny, z2 = nz*nz;               \
            float* o = s_sh + 9 * (k);                                    \
            o[0] = 1.0f;                                                  \
            o[1] = SQRT3 * nx;                                            \
            o[2] = SQRT3 * ny;                                            \
            o[3] = SQRT3 * nz;                                            \
            o[4] = SQRT5 * SQRT3 * nx * nz;                               \
            o[5] = SQRT5 * SQRT3 * nx * ny;                               \
            o[6] = SQRT5 * (y2 - 0.5f * (x2 + z2));                       \
            o[7] = SQRT5 * SQRT3 * ny * nz;                               \
            o[8] = SQRT5 * 0.5f * SQRT3 * (z2 - x2);                      \
        }
        if (tid < nblk)
            EDGE_COMPUTE(tid,       aAx,aAy,aAz, bAx,bAy,bAz, hAx,hAy,hAz);
        if (tid + 256 < nblk)
            EDGE_COMPUTE(tid + 256, aBx,aBy,aBz, bBx,bBy,bBz, hBx,hBy,hBz);
#undef EDGE_COMPUTE
        __syncthreads();

        // ---- flush s_sh -> out_sh (full-line nt v4f) ----
        if (nblk == 512) {
            v4f* gs = reinterpret_cast<v4f*>(out_sh + 9 * (size_t)base);
            const v4f* ls = reinterpret_cast<const v4f*>(s_sh);  // 1152 v4f
            NTS(ls[tid],        &gs[tid]);
            NTS(ls[tid + 256],  &gs[tid + 256]);
            NTS(ls[tid + 512],  &gs[tid + 512]);
            NTS(ls[tid + 768],  &gs[tid + 768]);
            if (tid < 128)
                NTS(ls[tid + 1024], &gs[tid + 1024]);
        } else {
            for (int i = tid; i < 9 * nblk; i += 256)
                out_sh[9 * (size_t)base + i] = s_sh[i];
        }

        if (!have_next) break;
        __syncthreads();   // WAR: next iteration rewrites s_sh

        // ---- rotate pipeline ----
        t_cur = t_nxt; t_nxt = t_n2;
        aAx=xaAx; aAy=xaAy; aAz=xaAz; bAx=xbAx; bAy=xbAy; bAz=xbAz;
        hAx=xhAx; hAy=xhAy; hAz=xhAz;
        aBx=xaBx; aBy=xaBy; aBz=xaBz; bBx=xbBx; bBy=xbBy; bBz=xbBz;
        hBx=xhBx; hBy=xhBy; hBz=xhBz;
        nAs=mAs; nAd=mAd; nBs=mBs; nBd=mBd;
    }
}

extern "C" void kernel_launch(void* const* d_in, const int* in_sizes, int n_in,
                              void* d_out, int out_size, void* d_ws, size_t ws_size,
                              hipStream_t stream) {
    const float* pos        = (const float*)d_in[0];
    const int*   edge_index = (const int*)d_in[1];
    const float* shift      = (const float*)d_in[2];

    const int n_edges = in_sizes[2] / 3;   // shift is [E,3]

    float* out_vec = (float*)d_out;                        // [E,3]
    float* out_len = (float*)d_out + 3 * (size_t)n_edges;  // [E]
    float* out_sh  = (float*)d_out + 4 * (size_t)n_edges;  // [E,9]

    const int n_tiles = (n_edges + 511) / 512;
    int blocks = n_tiles < 2048 ? n_tiles : 2048;  // 8 blocks/CU (LDS-limited)
    sh_edge_kernel<<<blocks, 256, 0, stream>>>(
        pos, edge_index, shift, out_vec, out_len, out_sh, n_edges);
}